// Round 1
// baseline (1102.904 us; speedup 1.0000x reference)
//
#include <hip/hip_runtime.h>

// GCN: out = relu( (X[i] + sum_{j in N(i)} X[j]) / deg[i] @ W )
// Strategy: Y = X@W first (linearity), then CSR-based gather-aggregate.
// ws layout: deg[N] | off[N+1] | cur[N] | adj[2E] | Y[N*128]  (~65.2 MB)

#define DFEAT 128

// ---------------- utility ----------------
__global__ void zero_kernel(int* p, int n) {
  int i = blockIdx.x * blockDim.x + threadIdx.x;
  if (i < n) p[i] = 0;
}

// Detect whether edge_list arrived as int64 (JAX x64 on) or int32 (x64 off).
// Under int64, the high 32-bit words of src[0],src[1] are 0.
// Under int32, el32[1] = src[1] = 1 (ring edge (1,2)) != 0.
__global__ void detect_kernel(const int* el32, int* flag) {
  if (threadIdx.x == 0 && blockIdx.x == 0) {
    flag[0] = (el32[1] == 0 && el32[3] == 0) ? 1 : 0;
  }
}

__device__ __forceinline__ int edge_at(const void* el, long long i, int mode64) {
  if (mode64) return (int)((const long long*)el)[i];
  return ((const int*)el)[i];
}

// ---------------- CSR build ----------------
__global__ void deg_kernel(const void* el, const int* __restrict__ flag,
                           int* __restrict__ deg, int E) {
  int e = blockIdx.x * blockDim.x + threadIdx.x;
  if (e >= E) return;
  int m = flag[0];
  int s = edge_at(el, e, m);
  int d = edge_at(el, (long long)E + e, m);
  atomicAdd(&deg[s], 1);
  atomicAdd(&deg[d], 1);
}

// Single-block exclusive scan over deg[0..n) -> off[0..n], copy to cur.
__global__ __launch_bounds__(1024) void scan_kernel(const int* __restrict__ deg,
                                                    int* __restrict__ off,
                                                    int* __restrict__ cur, int n) {
  __shared__ int sums[1024];
  int t = threadIdx.x;
  int C = (n + 1023) >> 10;  // elements per thread
  int start = t * C;
  int end = start + C; if (end > n) end = n;
  int s = 0;
  for (int i = start; i < end; i++) s += deg[i];
  sums[t] = s;
  __syncthreads();
  for (int d = 1; d < 1024; d <<= 1) {
    int add = (t >= d) ? sums[t - d] : 0;
    __syncthreads();
    sums[t] += add;
    __syncthreads();
  }
  int prefix = sums[t] - s;  // exclusive prefix of this thread's chunk
  for (int i = start; i < end; i++) {
    off[i] = prefix; cur[i] = prefix; prefix += deg[i];
  }
  if (start < n && end == n) off[n] = prefix;  // total = 2E
}

__global__ void fill_kernel(const void* el, const int* __restrict__ flag,
                            int* __restrict__ cur, int* __restrict__ adj, int E) {
  int e = blockIdx.x * blockDim.x + threadIdx.x;
  if (e >= E) return;
  int m = flag[0];
  int s = edge_at(el, e, m);
  int d = edge_at(el, (long long)E + e, m);
  adj[atomicAdd(&cur[s], 1)] = d;
  adj[atomicAdd(&cur[d], 1)] = s;
}

// ---------------- Y = X @ W (fp32 vector ALU; W in LDS, A via shuffles) ----
// Block = 1024 threads = 16 waves; each wave computes 4 rows; 64 rows/block.
__global__ __launch_bounds__(1024) void gemm_kernel(const float* __restrict__ X,
                                                    const float* __restrict__ W,
                                                    float* __restrict__ Y, int n) {
  __shared__ float Wl[DFEAT * DFEAT];  // 64 KB
  for (int t = threadIdx.x; t < DFEAT * DFEAT / 4; t += 1024)
    ((float4*)Wl)[t] = ((const float4*)W)[t];

  int wave = threadIdx.x >> 6;
  int lane = threadIdx.x & 63;
  int row0 = blockIdx.x * 64 + wave * 4;

  const float2* X2 = (const float2*)X;
  float2 x[4];
#pragma unroll
  for (int r = 0; r < 4; r++) {
    int row = row0 + r;
    if (row < n) x[r] = X2[(long long)row * 64 + lane];
    else { x[r].x = 0.f; x[r].y = 0.f; }
  }
  __syncthreads();

  float2 acc[4];
#pragma unroll
  for (int r = 0; r < 4; r++) { acc[r].x = 0.f; acc[r].y = 0.f; }

  const float2* W2 = (const float2*)Wl;
  for (int kk = 0; kk < 64; kk++) {
    // W rows 2kk and 2kk+1, columns (2*lane, 2*lane+1)
    float2 w0 = W2[(2 * kk) * 64 + lane];
    float2 w1 = W2[(2 * kk + 1) * 64 + lane];
#pragma unroll
    for (int r = 0; r < 4; r++) {
      float a0 = __shfl(x[r].x, kk);  // element 2kk of row r
      float a1 = __shfl(x[r].y, kk);  // element 2kk+1
      acc[r].x += a0 * w0.x + a1 * w1.x;
      acc[r].y += a0 * w0.y + a1 * w1.y;
    }
  }

  float2* Y2 = (float2*)Y;
#pragma unroll
  for (int r = 0; r < 4; r++) {
    int row = row0 + r;
    if (row < n) Y2[(long long)row * 64 + lane] = acc[r];
  }
}

// ---------------- gather-aggregate + scale + relu ----------------
// One wave per node; lane l owns features (2l, 2l+1).
__global__ __launch_bounds__(256) void gather_kernel(const float2* __restrict__ Y2,
                                                     const int* __restrict__ off,
                                                     const int* __restrict__ adj,
                                                     float2* __restrict__ out2, int n) {
  int wid = (int)((blockIdx.x * (long long)blockDim.x + threadIdx.x) >> 6);
  int lane = threadIdx.x & 63;
  if (wid >= n) return;

  int off0 = off[wid], off1 = off[wid + 1];
  float2 acc = Y2[(long long)wid * 64 + lane];  // self contribution

  for (int base = off0; base < off1; base += 64) {
    int cnt = off1 - base; if (cnt > 64) cnt = 64;
    int idx = (lane < cnt) ? adj[base + lane] : 0;
    int t = 0;
    for (; t + 4 <= cnt; t += 4) {
      int j0 = __shfl(idx, t);
      int j1 = __shfl(idx, t + 1);
      int j2 = __shfl(idx, t + 2);
      int j3 = __shfl(idx, t + 3);
      float2 v0 = Y2[(long long)j0 * 64 + lane];
      float2 v1 = Y2[(long long)j1 * 64 + lane];
      float2 v2 = Y2[(long long)j2 * 64 + lane];
      float2 v3 = Y2[(long long)j3 * 64 + lane];
      acc.x += v0.x + v1.x + v2.x + v3.x;
      acc.y += v0.y + v1.y + v2.y + v3.y;
    }
    for (; t < cnt; t++) {
      int j = __shfl(idx, t);
      float2 v = Y2[(long long)j * 64 + lane];
      acc.x += v.x; acc.y += v.y;
    }
  }

  float invd = 1.0f / (float)(off1 - off0);
  acc.x *= invd; acc.y *= invd;
  acc.x = acc.x > 0.f ? acc.x : 0.f;
  acc.y = acc.y > 0.f ? acc.y : 0.f;
  out2[(long long)wid * 64 + lane] = acc;
}

// ---------------- launch ----------------
extern "C" void kernel_launch(void* const* d_in, const int* in_sizes, int n_in,
                              void* d_out, int out_size, void* d_ws, size_t ws_size,
                              hipStream_t stream) {
  const float* X = (const float*)d_in[0];
  const float* W = (const float*)d_in[1];
  const void* el = d_in[2];
  float* out = (float*)d_out;

  int n = in_sizes[0] / DFEAT;   // 100000
  int E = in_sizes[2] / 2;       // 1600000

  char* p = (char*)d_ws;
  auto alloc = [&](size_t bytes) -> char* {
    char* q = p;
    p += (bytes + 511) & ~(size_t)511;
    return q;
  };
  int*   deg  = (int*)alloc((size_t)n * 4);
  int*   off  = (int*)alloc((size_t)(n + 1) * 4);
  int*   cur  = (int*)alloc((size_t)n * 4);
  int*   adj  = (int*)alloc((size_t)2 * E * 4);
  int*   flag = (int*)alloc(64);
  float* Y    = (float*)alloc((size_t)n * DFEAT * 4);

  detect_kernel<<<1, 64, 0, stream>>>((const int*)el, flag);
  zero_kernel<<<(n + 255) / 256, 256, 0, stream>>>(deg, n);
  deg_kernel<<<(E + 255) / 256, 256, 0, stream>>>(el, flag, deg, E);
  scan_kernel<<<1, 1024, 0, stream>>>(deg, off, cur, n);
  fill_kernel<<<(E + 255) / 256, 256, 0, stream>>>(el, flag, cur, adj, E);
  gemm_kernel<<<(n + 63) / 64, 1024, 0, stream>>>(X, W, Y, n);
  gather_kernel<<<(n + 3) / 4, 256, 0, stream>>>((const float2*)Y, off, adj,
                                                 (float2*)out, n);
}